// Round 14
// baseline (91.722 us; speedup 1.0000x reference)
//
#include <hip/hip_runtime.h>
#include <math.h>

#define NBATCH 4
#define NPTS   8192
#define KNN    8
#define NCH    4096
#define SLICES 16
#define SLEN   512               // candidates per slice-wave
#define NWIN   8                 // windows per slice
#define WLEN   64                // candidates per window
#define CTR_OFF 56
#define PB_OFF  256                                  // f32 pair buffer, 32B/pair
#define C2_OFF  (PB_OFF + NBATCH * (NPTS / 2) * 32)
#define BND_BLOCKS  32
#define SCAN_BLOCKS (NBATCH * (NPTS / 64))           // 512
#define TOT_BLOCKS  (BND_BLOCKS + SCAN_BLOCKS)       // 544

typedef float v2f __attribute__((ext_vector_type(2)));

__device__ __forceinline__ unsigned umin32(unsigned a, unsigned b) { return a < b ? a : b; }

// single-block insert: 8 instrs, bd pinned via tied "+v", in-place descending
// order reads only pre-block values => depth-1 sorted insert (ascending top-8).
// Used ONLY in the merge phases (not the hot scan loop).
#define INSERT8(bd, key)                                          \
    asm("v_med3_u32 %7, %8, %6, %7\n\t"                           \
        "v_med3_u32 %6, %8, %5, %6\n\t"                           \
        "v_med3_u32 %5, %8, %4, %5\n\t"                           \
        "v_med3_u32 %4, %8, %3, %4\n\t"                           \
        "v_med3_u32 %3, %8, %2, %3\n\t"                           \
        "v_med3_u32 %2, %8, %1, %2\n\t"                           \
        "v_med3_u32 %1, %8, %0, %1\n\t"                           \
        "v_min_u32  %0, %0, %8"                                   \
        : "+v"(bd[0]), "+v"(bd[1]), "+v"(bd[2]), "+v"(bd[3]),     \
          "+v"(bd[4]), "+v"(bd[5]), "+v"(bd[6]), "+v"(bd[7])      \
        : "v"(key))

// evaluate one f32 pair {x0,x1,y0,y1 | z0,z1,w0,w1} against query consts;
// returns packed 26-bit-d2|6-bit-idx window keys folded into wm0/wm1
#define PAIR_EVAL(PTR, J, wm0, wm1)                                          \
    do {                                                                     \
        const float4 ab = *reinterpret_cast<const float4*>((PTR) + (J) * 8); \
        const float4 cd = *reinterpret_cast<const float4*>((PTR) + (J) * 8 + 4); \
        const v2f xp = {ab.x, ab.y}, yp = {ab.z, ab.w};                      \
        const v2f zp = {cd.x, cd.y};                                         \
        v2f s2 = {cd.z, cd.w};                                               \
        s2 += qnp2;                                                          \
        s2 = __builtin_elementwise_fma(zp, m2z2, s2);                        \
        s2 = __builtin_elementwise_fma(yp, m2y2, s2);                        \
        s2 = __builtin_elementwise_fma(xp, m2x2, s2);                        \
        wm0 = umin32(wm0, (__float_as_uint(s2.x) & 0xFFFFFFC0u) | (unsigned)(2 * (J))); \
        wm1 = umin32(wm1, (__float_as_uint(s2.y) & 0xFFFFFFC0u) | (unsigned)(2 * (J) + 1)); \
    } while (0)

// prep (512 thr x 86 blocks): [0,32) pred->f32 pair buffer; [32,36) c2->pair
// buffer; [36,84) recon MSE (float4); [84,86) percep MSE (float4).
// acc/ctr are zeroed by hipMemsetAsync before this kernel (no race).
__global__ __launch_bounds__(512) void prep_kernel(const float* __restrict__ pts,
                                                   const float* __restrict__ c2,
                                                   const float* __restrict__ a,
                                                   const float* __restrict__ bt,
                                                   const float* __restrict__ a2,
                                                   const float* __restrict__ b2,
                                                   float* __restrict__ pb,
                                                   float* __restrict__ c2p,
                                                   double* __restrict__ acc) {
    __shared__ float red[8];
    const int t = threadIdx.x;
    const int blk = blockIdx.x;
    if (blk < 36) {
        const float* src;
        float* dst;
        int pi;
        if (blk < 32) { src = pts; dst = pb; pi = blk * 512 + t; }
        else { src = c2; dst = c2p; pi = (blk - 32) * 512 + t; }
        const float* s = src + (size_t)pi * 6;
        const float x0 = s[0], y0 = s[1], z0 = s[2];
        const float x1 = s[3], y1 = s[4], z1 = s[5];
        float4* o = reinterpret_cast<float4*>(dst + (size_t)pi * 8);
        o[0] = make_float4(x0, x1, y0, y1);
        o[1] = make_float4(z0, z1, x0 * x0 + y0 * y0 + z0 * z0,
                                   x1 * x1 + y1 * y1 + z1 * z1);
        return;
    }
    float s;
    int which;
    if (blk < 84) {
        which = 0;
        const int i = (blk - 36) * 512 + t;
        const float4 va = reinterpret_cast<const float4*>(a)[i];
        const float4 vb = reinterpret_cast<const float4*>(bt)[i];
        const float dx = va.x - vb.x, dy = va.y - vb.y;
        const float dz = va.z - vb.z, dw = va.w - vb.w;
        s = dx * dx + dy * dy + dz * dz + dw * dw;
    } else {
        which = 1;
        const int i = (blk - 84) * 512 + t;
        const float4 va = reinterpret_cast<const float4*>(a2)[i];
        const float4 vb = reinterpret_cast<const float4*>(b2)[i];
        const float dx = va.x - vb.x, dy = va.y - vb.y;
        const float dz = va.z - vb.z, dw = va.w - vb.w;
        s = dx * dx + dy * dy + dz * dz + dw * dw;
    }
#pragma unroll
    for (int o = 32; o > 0; o >>= 1) s += __shfl_down(s, o, 64);
    if ((t & 63) == 0) red[t >> 6] = s;
    __syncthreads();
    if (t == 0) {
        float bs = 0.f;
#pragma unroll
        for (int i = 0; i < 8; ++i) bs += red[i];
        atomicAdd(&acc[which], (double)bs);
    }
}

// Main kernel, 544 blocks x 1024 thr.
// Blocks [0,32): boundary — 128 queries/block (2 groups x 64 lanes), 16 waves;
//   each of 8 waves per group scans 256 c2-pairs via wave-uniform s_loads.
// Blocks [32,544): continuity kNN scan — 16 slice-waves x 64 shared queries;
//   each wave scans 8 windows of 64: windows 0-3 via the SCALAR pipe (s_load,
//   lgkmcnt full-drain) pair-interleaved with windows 4-7 via the VECTOR pipe
//   (laundered VGPR offset -> global_load_dwordx4, incremental vmcnt) so the
//   two memory pipes cover each other's stalls. Window minima -> exact med3
//   top-8 merge (self filtered by index), closed-form deviation sum from pred.
// Last-finished of all 544 blocks writes the 5 outputs.
__global__ __launch_bounds__(1024, 8) void main_kernel(const float* __restrict__ pb,
                                                       const float* __restrict__ pred,
                                                       const float* __restrict__ c1,
                                                       const float* __restrict__ c2p,
                                                       double* __restrict__ acc,
                                                       unsigned* __restrict__ ctr,
                                                       float* __restrict__ out) {
    __shared__ unsigned mrg[SLICES][KNN][64];   // 32 KB (bnd aliases a corner)
    const int t    = threadIdx.x;
    const int lane = t & 63;
    const int w    = __builtin_amdgcn_readfirstlane(t >> 6);   // wave id (SGPR)

    if (blockIdx.x < BND_BLOCKS) {
        float* mn = (float*)mrg;                // [2][8][64]
        const int g  = w >> 3;                  // query group 0/1
        const int wg = w & 7;                   // pair-segment within group
        const int qi = blockIdx.x * 128 + g * 64 + lane;
        const float qx = c1[qi * 3 + 0];
        const float qy = c1[qi * 3 + 1];
        const float qz = c1[qi * 3 + 2];
        const float qn = qx * qx + qy * qy + qz * qz;
        const v2f m2x2 = {-2.f * qx, -2.f * qx};
        const v2f m2y2 = {-2.f * qy, -2.f * qy};
        const v2f m2z2 = {-2.f * qz, -2.f * qz};
        float m = 3.0e38f;
        const float* __restrict__ Sp = c2p + (size_t)wg * 256 * 8;   // 256 pairs
#pragma unroll 16
        for (int j = 0; j < 256; ++j) {
            const float4 ab = *reinterpret_cast<const float4*>(Sp + j * 8);
            const float4 cd = *reinterpret_cast<const float4*>(Sp + j * 8 + 4);
            const v2f xp = {ab.x, ab.y}, yp = {ab.z, ab.w};
            const v2f zp = {cd.x, cd.y};
            v2f s2 = {cd.z, cd.w};
            s2 = __builtin_elementwise_fma(zp, m2z2, s2);
            s2 = __builtin_elementwise_fma(yp, m2y2, s2);
            s2 = __builtin_elementwise_fma(xp, m2x2, s2);
            m = fminf(m, fminf(s2.x, s2.y));
        }
        mn[(g * 8 + wg) * 64 + lane] = m;
        __syncthreads();
        if (wg == 0) {
            float mm = mn[g * 512 + lane];
#pragma unroll
            for (int s = 1; s < 8; ++s) mm = fminf(mm, mn[g * 512 + s * 64 + lane]);
            const float d = sqrtf(fmaxf(mm + qn, 0.f));
            const bool in = d < 0.1f;
            float sc = in ? d : 0.f;
            float sn = in ? 1.f : 0.f;
#pragma unroll
            for (int o = 32; o > 0; o >>= 1) {
                sc += __shfl_down(sc, o, 64);
                sn += __shfl_down(sn, o, 64);
            }
            if (lane == 0) {
                atomicAdd(&acc[3], (double)sc);
                atomicAdd(&acc[4], (double)sn);
            }
        }
    } else {
        const int blk2 = blockIdx.x - BND_BLOCKS;
        const int nqw  = NPTS / 64;
        const int b    = blk2 / nqw;
        const int q0   = (blk2 % nqw) * 64;
        const float* __restrict__ B = pb + (size_t)b * (NPTS / 2) * 8;

        const int qi = q0 + lane;
        const float* qp = B + (size_t)(qi >> 1) * 8;
        const int e = qi & 1;
        const float qx = qp[0 + e], qy = qp[2 + e], qz = qp[4 + e], qw = qp[6 + e];
        const v2f qnp2 = {qw + 1e-6f, qw + 1e-6f};
        const v2f m2x2 = {-2.f * qx, -2.f * qx};
        const v2f m2y2 = {-2.f * qy, -2.f * qy};
        const v2f m2z2 = {-2.f * qz, -2.f * qz};

        const float* __restrict__ Sp = B + (size_t)w * SLEN * 4;   // scalar base
        int voff = w * (SLEN * 4);
        asm("" : "+v"(voff));                   // launder -> vector-pipe loads
        const float* __restrict__ Bv = B + voff;

        const unsigned jb = (unsigned)(w * SLEN);
        unsigned keyout[NWIN];

#pragma unroll
        for (int wp = 0; wp < 4; ++wp) {
            const float* __restrict__ Ws = Sp + wp * (WLEN * 4);         // scalar win wp
            const float* __restrict__ Wv = Bv + (wp + 4) * (WLEN * 4);   // vector win wp+4
            unsigned mS0 = 0xFFFFFFFFu, mS1 = 0xFFFFFFFFu;
            unsigned mV0 = 0xFFFFFFFFu, mV1 = 0xFFFFFFFFu;
#pragma unroll
            for (int j = 0; j < WLEN / 2; ++j) {
                PAIR_EVAL(Ws, j, mS0, mS1);     // SMEM pipe
                PAIR_EVAL(Wv, j, mV0, mV1);     // VMEM pipe
            }
            const unsigned wmS = umin32(mS0, mS1);
            const unsigned wmV = umin32(mV0, mV1);
            keyout[wp]     = (wmS & 0xFFFFE000u) | (jb + (unsigned)(wp * WLEN)) | (wmS & 63u);
            keyout[wp + 4] = (wmV & 0xFFFFE000u) | (jb + (unsigned)((wp + 4) * WLEN)) | (wmV & 63u);
        }

#pragma unroll
        for (int wi = 0; wi < NWIN; ++wi) mrg[w][wi][lane] = keyout[wi];
        __syncthreads();

        // stage 1: waves 0..3 each merge 4 slices' window minima (self filtered)
        if (w < 4) {
            const unsigned selfidx = (unsigned)qi;
            unsigned best[KNN];
#pragma unroll
            for (int s = 0; s < KNN; ++s) best[s] = 0xFFFFFFFFu;
            for (int sl = 4 * w; sl < 4 * w + 4; ++sl) {
#pragma unroll
                for (int u = 0; u < KNN; ++u) {
                    unsigned key = mrg[sl][u][lane];
                    key = ((key & 0x1FFFu) == selfidx) ? 0xFFFFFFFFu : key;
                    INSERT8(best, key);
                }
            }
#pragma unroll
            for (int s = 0; s < KNN; ++s) mrg[4 * w][s][lane] = best[s];
        }
        __syncthreads();

        // stage 2: wave 0 merges the 4 partials; deviation sum from f32 pred
        if (w == 0) {
            unsigned best[KNN];
#pragma unroll
            for (int s = 0; s < KNN; ++s) best[s] = 0xFFFFFFFFu;
            for (int g = 0; g < 4; ++g) {
#pragma unroll
                for (int u = 0; u < KNN; ++u) {
                    const unsigned key = mrg[4 * g][u][lane];
                    INSERT8(best, key);
                }
            }
            const float* __restrict__ P = pred + (size_t)b * NPTS * 3;
            float sx = 0.f, sy = 0.f, sz = 0.f, sw = 0.f;
#pragma unroll
            for (int s = 0; s < KNN; ++s) {
                const unsigned n = best[s] & 0x1FFFu;
                const float* np = P + (size_t)n * 3;
                const float x = np[0], y = np[1], z = np[2];
                sx += x; sy += y; sz += z;
                sw += x * x + y * y + z * z;
            }
            float ssum = sw - (sx * sx + sy * sy + sz * sz) * (1.f / KNN);
#pragma unroll
            for (int o = 32; o > 0; o >>= 1) ssum += __shfl_down(ssum, o, 64);
            if (lane == 0) atomicAdd(&acc[2], (double)ssum);
        }
    }

    // last-done block finalizes the 5 outputs
    __syncthreads();
    if (t == 0) {
        __threadfence();
        const unsigned old = atomicAdd(ctr, 1u);
        if (old == TOT_BLOCKS - 1) {
            __threadfence();
            const double a0 = atomicAdd(&acc[0], 0.0);
            const double a1 = atomicAdd(&acc[1], 0.0);
            const double a2d = atomicAdd(&acc[2], 0.0);
            const double a3 = atomicAdd(&acc[3], 0.0);
            const double a4 = atomicAdd(&acc[4], 0.0);
            const double recon  = a0 / (double)(NBATCH * NPTS * 3);
            const double percep = a1 / 4096.0;
            const double cont   = a2d / (double)(NBATCH * NPTS * KNN);
            const double bnd    = (a4 > 0.0) ? a3 / ((a4 > 1.0) ? a4 : 1.0) : 0.0;
            const double total  = recon + 0.5 * percep + 0.5 * cont + bnd;
            out[0] = (float)recon;
            out[1] = (float)percep;
            out[2] = (float)cont;
            out[3] = (float)bnd;
            out[4] = (float)total;
        }
    }
}

extern "C" void kernel_launch(void* const* d_in, const int* in_sizes, int n_in,
                              void* d_out, int out_size, void* d_ws, size_t ws_size,
                              hipStream_t stream) {
    const float* pred = (const float*)d_in[0];
    const float* targ = (const float*)d_in[1];
    const float* pf   = (const float*)d_in[2];
    const float* tf   = (const float*)d_in[3];
    const float* c1   = (const float*)d_in[4];
    const float* c2   = (const float*)d_in[5];
    float* out  = (float*)d_out;
    double* acc = (double*)d_ws;
    unsigned* ctr = (unsigned*)((char*)d_ws + CTR_OFF);
    float* pb   = (float*)((char*)d_ws + PB_OFF);
    float* c2p  = (float*)((char*)d_ws + C2_OFF);

    hipMemsetAsync(d_ws, 0, 64, stream);   // acc[0..4] + ctr
    hipLaunchKernelGGL(prep_kernel, dim3(86), dim3(512), 0, stream,
                       pred, c2, pred, targ, pf, tf, pb, c2p, acc);
    hipLaunchKernelGGL(main_kernel, dim3(TOT_BLOCKS), dim3(1024), 0, stream,
                       pb, pred, c1, c2p, acc, ctr, out);
}

// Round 15
// 72.269 us; speedup vs baseline: 1.2692x; 1.2692x over previous
//
#include <hip/hip_runtime.h>
#include <math.h>

#define NBATCH 4
#define NPTS   8192
#define KNN    8
#define NCH    4096
#define SLICES 16
#define SLEN   512               // candidates per slice-wave
#define NWIN   8                 // windows per slice
#define WLEN   64                // candidates per window
#define CTR_OFF 64
#define PB_OFF  256                                   // f16 octet buffer (48B/8 cand)
#define C2_OFF  (PB_OFF + (NBATCH * NPTS / 8) * 48)   // f32 c2 pair buffer
#define NAUX   114               // 48 recon + 2 percep + 64 bnd blocks

typedef float    v2f __attribute__((ext_vector_type(2)));
typedef _Float16 v2h __attribute__((ext_vector_type(2)));

__device__ __forceinline__ unsigned umin32(unsigned a, unsigned b) { return a < b ? a : b; }
__device__ __forceinline__ unsigned h2u(v2h v) { unsigned u; __builtin_memcpy(&u, &v, 4); return u; }
__device__ __forceinline__ v2h u2h(unsigned u) { v2h v; __builtin_memcpy(&v, &u, 4); return v; }

// single-block insert: 8 instrs, bd pinned via tied "+v", in-place descending
// order reads only pre-block values => depth-1 sorted insert (ascending top-8).
// Used ONLY in the merge phases (not the hot scan loop).
#define INSERT8(bd, key)                                          \
    asm("v_med3_u32 %7, %8, %6, %7\n\t"                           \
        "v_med3_u32 %6, %8, %5, %6\n\t"                           \
        "v_med3_u32 %5, %8, %4, %5\n\t"                           \
        "v_med3_u32 %4, %8, %3, %4\n\t"                           \
        "v_med3_u32 %3, %8, %2, %3\n\t"                           \
        "v_med3_u32 %2, %8, %1, %2\n\t"                           \
        "v_med3_u32 %1, %8, %0, %1\n\t"                           \
        "v_min_u32  %0, %0, %8"                                   \
        : "+v"(bd[0]), "+v"(bd[1]), "+v"(bd[2]), "+v"(bd[3]),     \
          "+v"(bd[4]), "+v"(bd[5]), "+v"(bd[6]), "+v"(bd[7])      \
        : "v"(key))

// pred -> f16 octets {x0..x7}{y0..y7}{z0..z7} (3 x 16B per 8 points);
// c2 -> f32 pair buffer; zeroes acc + ctr.
__global__ __launch_bounds__(256) void prep_kernel(const float* __restrict__ pts,
                                                   const float* __restrict__ c2,
                                                   unsigned* __restrict__ pb16,
                                                   float* __restrict__ c2p,
                                                   double* __restrict__ acc,
                                                   unsigned* __restrict__ ctr) {
    const int gi = blockIdx.x * 256 + threadIdx.x;
    if (gi < 8) acc[gi] = 0.0;
    if (gi == 8) *ctr = 0u;
    if (gi < NBATCH * NPTS / 8) {               // 4096 octet tasks
        const float* s = pts + (size_t)gi * 24;
        unsigned* o = pb16 + (size_t)gi * 12;
#pragma unroll
        for (int k = 0; k < 4; ++k) {
            const v2h xp = {(_Float16)s[(2 * k) * 3 + 0], (_Float16)s[(2 * k + 1) * 3 + 0]};
            const v2h yp = {(_Float16)s[(2 * k) * 3 + 1], (_Float16)s[(2 * k + 1) * 3 + 1]};
            const v2h zp = {(_Float16)s[(2 * k) * 3 + 2], (_Float16)s[(2 * k + 1) * 3 + 2]};
            o[k] = h2u(xp);
            o[4 + k] = h2u(yp);
            o[8 + k] = h2u(zp);
        }
    } else if (gi < NBATCH * NPTS / 8 + NCH / 2) {   // 2048 c2 pair tasks
        const int pi = gi - NBATCH * NPTS / 8;
        const float* s = c2 + (size_t)pi * 6;
        const float x0 = s[0], y0 = s[1], z0 = s[2];
        const float x1 = s[3], y1 = s[4], z1 = s[5];
        float4* o = reinterpret_cast<float4*>(c2p + (size_t)pi * 8);
        o[0] = make_float4(x0, x1, y0, y1);
        o[1] = make_float4(z0, z1, x0 * x0 + y0 * y0 + z0 * z0,
                                   x1 * x1 + y1 * y1 + z1 * z1);
    }
}

// Continuity kNN, window-min + f16 octet stream: block = 16 slice-waves; every
// wave holds the SAME 64 queries (one per lane), scans its 512-candidate slice
// as 8 windows of 64 via wave-uniform s_load_dwordx4 of f16 octets (6B/cand —
// ~40 candidates in flight per SGPR budget, covering scalar-L2 latency).
// Distance in f16 difference form (no cancellation; self d2 == +0 exactly).
// Window min key = f16 d2 bits[31:16] | local idx[5:0]; re-packed to global
// idx[12:0]; exact med3 top-8 merge, self filtered by index. Deviation gather
// and queries from f32 pred (query f16 conversion matches prep's).
__global__ __launch_bounds__(1024, 8) void cont_kernel(const unsigned* __restrict__ pb16,
                                                       const float* __restrict__ pred,
                                                       double* __restrict__ acc) {
    __shared__ unsigned mrg[SLICES][KNN][64];   // 32 KB, lane-consecutive
    const int t    = threadIdx.x;
    const int lane = t & 63;
    const int w    = __builtin_amdgcn_readfirstlane(t >> 6);   // slice id (SGPR)
    const int nqw  = NPTS / 64;
    const int b    = blockIdx.x / nqw;
    const int q0   = (blockIdx.x % nqw) * 64;
    const unsigned* __restrict__ B16 = pb16 + (size_t)b * (NPTS / 8) * 12;
    const float* __restrict__ P = pred + (size_t)b * NPTS * 3;

    const int qi = q0 + lane;
    const _Float16 qxh = (_Float16)P[qi * 3 + 0];
    const _Float16 qyh = (_Float16)P[qi * 3 + 1];
    const _Float16 qzh = (_Float16)P[qi * 3 + 2];
    const v2h qx2 = {qxh, qxh}, qy2 = {qyh, qyh}, qz2 = {qzh, qzh};

    const unsigned* __restrict__ Sp = B16 + (size_t)w * (SLEN / 8) * 12;  // 768 dwords
    const unsigned jb = (unsigned)(w * SLEN);
    unsigned keyout[NWIN];

#pragma unroll
    for (int wi = 0; wi < NWIN; ++wi) {
        const unsigned* __restrict__ Wp = Sp + wi * 96;   // 8 octets x 12 dwords
        unsigned wmA = 0xFFFFFFFFu, wmB = 0xFFFFFFFFu;
#pragma unroll
        for (int o = 0; o < 8; ++o) {
            const uint4 xo = *reinterpret_cast<const uint4*>(Wp + o * 12);
            const uint4 yo = *reinterpret_cast<const uint4*>(Wp + o * 12 + 4);
            const uint4 zo = *reinterpret_cast<const uint4*>(Wp + o * 12 + 8);
            const unsigned xa[4] = {xo.x, xo.y, xo.z, xo.w};
            const unsigned ya[4] = {yo.x, yo.y, yo.z, yo.w};
            const unsigned za[4] = {zo.x, zo.y, zo.z, zo.w};
#pragma unroll
            for (int k = 0; k < 4; ++k) {
                const v2h dx = u2h(xa[k]) - qx2;
                const v2h dy = u2h(ya[k]) - qy2;
                const v2h dz = u2h(za[k]) - qz2;
                v2h d2 = dx * dx;
                d2 = __builtin_elementwise_fma(dy, dy, d2);
                d2 = __builtin_elementwise_fma(dz, dz, d2);
                const unsigned bits = h2u(d2);
                const unsigned i0 = (unsigned)(o * 8 + 2 * k);        // compile-time
                const unsigned k0 = (bits << 16) | i0;                // lshl_or
                const unsigned k1 = (bits & 0xFFFF0000u) | (i0 + 1);  // and_or
                wmA = umin32(wmA, k0);
                wmB = umin32(wmB, k1);
            }
        }
        const unsigned wm = umin32(wmA, wmB);
        keyout[wi] = (wm & 0xFFFF0000u) | (jb + (unsigned)(wi * WLEN)) | (wm & 63u);
    }

#pragma unroll
    for (int wi = 0; wi < NWIN; ++wi) mrg[w][wi][lane] = keyout[wi];
    __syncthreads();

    // stage 1: waves 0..3 each merge 4 slices' window minima (self filtered)
    if (w < 4) {
        const unsigned selfidx = (unsigned)qi;
        unsigned best[KNN];
#pragma unroll
        for (int s = 0; s < KNN; ++s) best[s] = 0xFFFFFFFFu;
        for (int sl = 4 * w; sl < 4 * w + 4; ++sl) {
#pragma unroll
            for (int u = 0; u < KNN; ++u) {
                unsigned key = mrg[sl][u][lane];
                key = ((key & 0x1FFFu) == selfidx) ? 0xFFFFFFFFu : key;
                INSERT8(best, key);
            }
        }
#pragma unroll
        for (int s = 0; s < KNN; ++s) mrg[4 * w][s][lane] = best[s];
    }
    __syncthreads();

    // stage 2: wave 0 merges the 4 partials; deviation sum from f32 pred
    if (w == 0) {
        unsigned best[KNN];
#pragma unroll
        for (int s = 0; s < KNN; ++s) best[s] = 0xFFFFFFFFu;
        for (int g = 0; g < 4; ++g) {
#pragma unroll
            for (int u = 0; u < KNN; ++u) {
                const unsigned key = mrg[4 * g][u][lane];
                INSERT8(best, key);
            }
        }
        float sx = 0.f, sy = 0.f, sz = 0.f, sw = 0.f;
#pragma unroll
        for (int s = 0; s < KNN; ++s) {
            const unsigned n = best[s] & 0x1FFFu;
            const float* np = P + (size_t)n * 3;
            const float x = np[0], y = np[1], z = np[2];
            sx += x; sy += y; sz += z;
            sw += x * x + y * y + z * z;
        }
        float ssum = sw - (sx * sx + sy * sy + sz * sz) * (1.f / KNN);
#pragma unroll
        for (int o = 32; o > 0; o >>= 1) ssum += __shfl_down(ssum, o, 64);
        if (lane == 0) atomicAdd(&acc[2], (double)ssum);
    }
}

// Fused aux (512 thr, 114 blocks): [0,48) recon MSE (float4), [48,50) percep
// (float4), [50,114) boundary G=1: 64 queries/block, 8 waves x 256 f32 c2-pairs
// via wave-uniform s_loads + packed min of |p|^2-2p.q; |q|^2 added once.
// Last finishing block computes the final 5 outputs.
__global__ __launch_bounds__(512) void aux_kernel(const float* __restrict__ a,
                                                  const float* __restrict__ bt,
                                                  const float* __restrict__ a2,
                                                  const float* __restrict__ b2,
                                                  const float* __restrict__ c1,
                                                  const float* __restrict__ c2p,
                                                  double* __restrict__ acc,
                                                  unsigned* __restrict__ ctr,
                                                  float* __restrict__ out) {
    __shared__ float smem[8 * 64];
    const int t = threadIdx.x;
    const int blk = blockIdx.x;
    if (blk < 50) {
        float s;
        int which;
        if (blk < 48) {
            which = 0;
            const int i = blk * 512 + t;
            const float4 va = reinterpret_cast<const float4*>(a)[i];
            const float4 vb = reinterpret_cast<const float4*>(bt)[i];
            const float dx = va.x - vb.x, dy = va.y - vb.y;
            const float dz = va.z - vb.z, dw = va.w - vb.w;
            s = dx * dx + dy * dy + dz * dz + dw * dw;
        } else {
            which = 1;
            const int i = (blk - 48) * 512 + t;
            const float4 va = reinterpret_cast<const float4*>(a2)[i];
            const float4 vb = reinterpret_cast<const float4*>(b2)[i];
            const float dx = va.x - vb.x, dy = va.y - vb.y;
            const float dz = va.z - vb.z, dw = va.w - vb.w;
            s = dx * dx + dy * dy + dz * dz + dw * dw;
        }
#pragma unroll
        for (int o = 32; o > 0; o >>= 1) s += __shfl_down(s, o, 64);
        if ((t & 63) == 0) smem[t >> 6] = s;
        __syncthreads();
        if (t == 0) {
            float bs = 0.f;
#pragma unroll
            for (int i = 0; i < 8; ++i) bs += smem[i];
            atomicAdd(&acc[which], (double)bs);
        }
    } else {
        const int lane = t & 63;
        const int w8 = __builtin_amdgcn_readfirstlane(t >> 6);   // 0..7
        const int qi = (blk - 50) * 64 + lane;
        const float qx = c1[qi * 3 + 0];
        const float qy = c1[qi * 3 + 1];
        const float qz = c1[qi * 3 + 2];
        const float qn = qx * qx + qy * qy + qz * qz;
        const v2f m2x2 = {-2.f * qx, -2.f * qx};
        const v2f m2y2 = {-2.f * qy, -2.f * qy};
        const v2f m2z2 = {-2.f * qz, -2.f * qz};
        float m = 3.0e38f;
        const float* __restrict__ Sp = c2p + (size_t)w8 * 256 * 8;   // 256 pairs
#pragma unroll 16
        for (int j = 0; j < 256; ++j) {
            const float4 ab = *reinterpret_cast<const float4*>(Sp + j * 8);
            const float4 cd = *reinterpret_cast<const float4*>(Sp + j * 8 + 4);
            const v2f xp = {ab.x, ab.y}, yp = {ab.z, ab.w};
            const v2f zp = {cd.x, cd.y};
            v2f s2 = {cd.z, cd.w};
            s2 = __builtin_elementwise_fma(zp, m2z2, s2);
            s2 = __builtin_elementwise_fma(yp, m2y2, s2);
            s2 = __builtin_elementwise_fma(xp, m2x2, s2);
            m = fminf(m, fminf(s2.x, s2.y));
        }
        smem[w8 * 64 + lane] = m;
        __syncthreads();
        if (w8 == 0) {
            float mm = smem[lane];
#pragma unroll
            for (int s = 1; s < 8; ++s) mm = fminf(mm, smem[s * 64 + lane]);
            const float d = sqrtf(fmaxf(mm + qn, 0.f));
            const bool in = d < 0.1f;
            float sc = in ? d : 0.f;
            float sn = in ? 1.f : 0.f;
#pragma unroll
            for (int o = 32; o > 0; o >>= 1) {
                sc += __shfl_down(sc, o, 64);
                sn += __shfl_down(sn, o, 64);
            }
            if (lane == 0) {
                atomicAdd(&acc[3], (double)sc);
                atomicAdd(&acc[4], (double)sn);
            }
        }
    }
    // last-done block finalizes the 5 outputs
    __syncthreads();
    if (t == 0) {
        __threadfence();
        const unsigned old = atomicAdd(ctr, 1u);
        if (old == NAUX - 1) {
            __threadfence();
            const double a0 = atomicAdd(&acc[0], 0.0);
            const double a1 = atomicAdd(&acc[1], 0.0);
            const double a2d = atomicAdd(&acc[2], 0.0);
            const double a3 = atomicAdd(&acc[3], 0.0);
            const double a4 = atomicAdd(&acc[4], 0.0);
            const double recon  = a0 / (double)(NBATCH * NPTS * 3);
            const double percep = a1 / 4096.0;
            const double cont   = a2d / (double)(NBATCH * NPTS * KNN);
            const double bnd    = (a4 > 0.0) ? a3 / ((a4 > 1.0) ? a4 : 1.0) : 0.0;
            const double total  = recon + 0.5 * percep + 0.5 * cont + bnd;
            out[0] = (float)recon;
            out[1] = (float)percep;
            out[2] = (float)cont;
            out[3] = (float)bnd;
            out[4] = (float)total;
        }
    }
}

extern "C" void kernel_launch(void* const* d_in, const int* in_sizes, int n_in,
                              void* d_out, int out_size, void* d_ws, size_t ws_size,
                              hipStream_t stream) {
    const float* pred = (const float*)d_in[0];
    const float* targ = (const float*)d_in[1];
    const float* pf   = (const float*)d_in[2];
    const float* tf   = (const float*)d_in[3];
    const float* c1   = (const float*)d_in[4];
    const float* c2   = (const float*)d_in[5];
    float* out  = (float*)d_out;
    double* acc = (double*)d_ws;
    unsigned* ctr = (unsigned*)((char*)d_ws + CTR_OFF);
    unsigned* pb16 = (unsigned*)((char*)d_ws + PB_OFF);
    float* c2p  = (float*)((char*)d_ws + C2_OFF);

    hipLaunchKernelGGL(prep_kernel, dim3(24), dim3(256), 0, stream,
                       pred, c2, pb16, c2p, acc, ctr);
    hipLaunchKernelGGL(cont_kernel, dim3(NBATCH * (NPTS / 64)), dim3(1024), 0, stream,
                       pb16, pred, acc);
    hipLaunchKernelGGL(aux_kernel, dim3(NAUX), dim3(512), 0, stream,
                       pred, targ, pf, tf, c1, c2p, acc, ctr, out);
}

// Round 16
// 71.141 us; speedup vs baseline: 1.2893x; 1.0159x over previous
//
#include <hip/hip_runtime.h>
#include <math.h>

#define NBATCH 4
#define NPTS   8192
#define KNN    8
#define NCH    4096
#define SLICES 16
#define SLEN   512               // candidates per slice-wave
#define NWIN   8                 // windows per slice
#define WLEN   64                // candidates per window
#define CTR_OFF 56
#define PB_OFF  256                                  // f32 pair buffer, 32B/pair
#define C2_OFF  (PB_OFF + NBATCH * (NPTS / 2) * 32)
#define BND_BLOCKS  32
#define SCAN_BLOCKS (NBATCH * (NPTS / 64))           // 512
#define TOT_BLOCKS  (BND_BLOCKS + SCAN_BLOCKS)       // 544

typedef float v2f __attribute__((ext_vector_type(2)));

__device__ __forceinline__ unsigned umin32(unsigned a, unsigned b) { return a < b ? a : b; }

// single-block insert: 8 instrs, bd pinned via tied "+v", in-place descending
// order reads only pre-block values => depth-1 sorted insert (ascending top-8).
// Used ONLY in the merge phases (not the hot scan loop).
#define INSERT8(bd, key)                                          \
    asm("v_med3_u32 %7, %8, %6, %7\n\t"                           \
        "v_med3_u32 %6, %8, %5, %6\n\t"                           \
        "v_med3_u32 %5, %8, %4, %5\n\t"                           \
        "v_med3_u32 %4, %8, %3, %4\n\t"                           \
        "v_med3_u32 %3, %8, %2, %3\n\t"                           \
        "v_med3_u32 %2, %8, %1, %2\n\t"                           \
        "v_med3_u32 %1, %8, %0, %1\n\t"                           \
        "v_min_u32  %0, %0, %8"                                   \
        : "+v"(bd[0]), "+v"(bd[1]), "+v"(bd[2]), "+v"(bd[3]),     \
          "+v"(bd[4]), "+v"(bd[5]), "+v"(bd[6]), "+v"(bd[7])      \
        : "v"(key))

// prep (512 thr x 86 blocks): [0,32) pred->f32 pair buffer; [32,36) c2->pair
// buffer; [36,84) recon MSE (float4); [84,86) percep MSE (float4).
// acc/ctr are zeroed by hipMemsetAsync before this kernel (no race).
__global__ __launch_bounds__(512) void prep_kernel(const float* __restrict__ pts,
                                                   const float* __restrict__ c2,
                                                   const float* __restrict__ a,
                                                   const float* __restrict__ bt,
                                                   const float* __restrict__ a2,
                                                   const float* __restrict__ b2,
                                                   float* __restrict__ pb,
                                                   float* __restrict__ c2p,
                                                   double* __restrict__ acc) {
    __shared__ float red[8];
    const int t = threadIdx.x;
    const int blk = blockIdx.x;
    if (blk < 36) {
        const float* src;
        float* dst;
        int pi;
        if (blk < 32) { src = pts; dst = pb; pi = blk * 512 + t; }
        else { src = c2; dst = c2p; pi = (blk - 32) * 512 + t; }
        const float* s = src + (size_t)pi * 6;
        const float x0 = s[0], y0 = s[1], z0 = s[2];
        const float x1 = s[3], y1 = s[4], z1 = s[5];
        float4* o = reinterpret_cast<float4*>(dst + (size_t)pi * 8);
        o[0] = make_float4(x0, x1, y0, y1);
        o[1] = make_float4(z0, z1, x0 * x0 + y0 * y0 + z0 * z0,
                                   x1 * x1 + y1 * y1 + z1 * z1);
        return;
    }
    float s;
    int which;
    if (blk < 84) {
        which = 0;
        const int i = (blk - 36) * 512 + t;
        const float4 va = reinterpret_cast<const float4*>(a)[i];
        const float4 vb = reinterpret_cast<const float4*>(bt)[i];
        const float dx = va.x - vb.x, dy = va.y - vb.y;
        const float dz = va.z - vb.z, dw = va.w - vb.w;
        s = dx * dx + dy * dy + dz * dz + dw * dw;
    } else {
        which = 1;
        const int i = (blk - 84) * 512 + t;
        const float4 va = reinterpret_cast<const float4*>(a2)[i];
        const float4 vb = reinterpret_cast<const float4*>(b2)[i];
        const float dx = va.x - vb.x, dy = va.y - vb.y;
        const float dz = va.z - vb.z, dw = va.w - vb.w;
        s = dx * dx + dy * dy + dz * dz + dw * dw;
    }
#pragma unroll
    for (int o = 32; o > 0; o >>= 1) s += __shfl_down(s, o, 64);
    if ((t & 63) == 0) red[t >> 6] = s;
    __syncthreads();
    if (t == 0) {
        float bs = 0.f;
#pragma unroll
        for (int i = 0; i < 8; ++i) bs += red[i];
        atomicAdd(&acc[which], (double)bs);
    }
}

// Main kernel, 544 blocks x 1024 thr.
// Blocks [0,32): boundary — 128 queries/block (2 groups x 64 lanes), 16 waves;
//   each of 8 waves per group scans 256 c2-pairs via wave-uniform s_loads.
// Blocks [32,544): continuity kNN — EXACT round-11 scan: 16 slice-waves x 64
//   shared queries; each wave scans its 512-candidate slice as 8 windows of 64
//   via wave-uniform scalar loads (plain C, compiler-pipelined s_load_dwordx4
//   batches). Window min keys (26-bit d2 | 6-bit idx) -> exact med3 top-8
//   merge (self filtered by index), closed-form deviation sum.
// Last-finished of all 544 blocks writes the 5 outputs.
__global__ __launch_bounds__(1024, 8) void main_kernel(const float* __restrict__ pb,
                                                       const float* __restrict__ pred,
                                                       const float* __restrict__ c1,
                                                       const float* __restrict__ c2p,
                                                       double* __restrict__ acc,
                                                       unsigned* __restrict__ ctr,
                                                       float* __restrict__ out) {
    __shared__ unsigned mrg[SLICES][KNN][64];   // 32 KB (bnd aliases a corner)
    const int t    = threadIdx.x;
    const int lane = t & 63;
    const int w    = __builtin_amdgcn_readfirstlane(t >> 6);   // wave id (SGPR)

    if (blockIdx.x < BND_BLOCKS) {
        float* mn = (float*)mrg;                // [2][8][64]
        const int g  = w >> 3;                  // query group 0/1
        const int wg = w & 7;                   // pair-segment within group
        const int qi = blockIdx.x * 128 + g * 64 + lane;
        const float qx = c1[qi * 3 + 0];
        const float qy = c1[qi * 3 + 1];
        const float qz = c1[qi * 3 + 2];
        const float qn = qx * qx + qy * qy + qz * qz;
        const v2f m2x2 = {-2.f * qx, -2.f * qx};
        const v2f m2y2 = {-2.f * qy, -2.f * qy};
        const v2f m2z2 = {-2.f * qz, -2.f * qz};
        float m = 3.0e38f;
        const float* __restrict__ Sp = c2p + (size_t)wg * 256 * 8;   // 256 pairs
#pragma unroll 16
        for (int j = 0; j < 256; ++j) {
            const float4 ab = *reinterpret_cast<const float4*>(Sp + j * 8);
            const float4 cd = *reinterpret_cast<const float4*>(Sp + j * 8 + 4);
            const v2f xp = {ab.x, ab.y}, yp = {ab.z, ab.w};
            const v2f zp = {cd.x, cd.y};
            v2f s2 = {cd.z, cd.w};
            s2 = __builtin_elementwise_fma(zp, m2z2, s2);
            s2 = __builtin_elementwise_fma(yp, m2y2, s2);
            s2 = __builtin_elementwise_fma(xp, m2x2, s2);
            m = fminf(m, fminf(s2.x, s2.y));
        }
        mn[(g * 8 + wg) * 64 + lane] = m;
        __syncthreads();
        if (wg == 0) {
            float mm = mn[g * 512 + lane];
#pragma unroll
            for (int s = 1; s < 8; ++s) mm = fminf(mm, mn[g * 512 + s * 64 + lane]);
            const float d = sqrtf(fmaxf(mm + qn, 0.f));
            const bool in = d < 0.1f;
            float sc = in ? d : 0.f;
            float sn = in ? 1.f : 0.f;
#pragma unroll
            for (int o = 32; o > 0; o >>= 1) {
                sc += __shfl_down(sc, o, 64);
                sn += __shfl_down(sn, o, 64);
            }
            if (lane == 0) {
                atomicAdd(&acc[3], (double)sc);
                atomicAdd(&acc[4], (double)sn);
            }
        }
    } else {
        const int blk2 = blockIdx.x - BND_BLOCKS;
        const int nqw  = NPTS / 64;
        const int b    = blk2 / nqw;
        const int q0   = (blk2 % nqw) * 64;
        const float* __restrict__ B = pb + (size_t)b * (NPTS / 2) * 8;

        const int qi = q0 + lane;
        const float* qp = B + (size_t)(qi >> 1) * 8;
        const int e = qi & 1;
        const float qx = qp[0 + e], qy = qp[2 + e], qz = qp[4 + e], qw = qp[6 + e];
        const v2f qnp2 = {qw + 1e-6f, qw + 1e-6f};
        const v2f m2x2 = {-2.f * qx, -2.f * qx};
        const v2f m2y2 = {-2.f * qy, -2.f * qy};
        const v2f m2z2 = {-2.f * qz, -2.f * qz};

        const float* __restrict__ Sp = B + (size_t)w * SLEN * 4;
        const unsigned jb = (unsigned)(w * SLEN);
        unsigned keyout[NWIN];

#pragma unroll
        for (int wi = 0; wi < NWIN; ++wi) {
            const float* __restrict__ Wp = Sp + wi * (WLEN * 4);
            unsigned wmA = 0xFFFFFFFFu, wmB = 0xFFFFFFFFu;
#pragma unroll
            for (int j = 0; j < WLEN / 2; ++j) {
                const float4 ab = *reinterpret_cast<const float4*>(Wp + j * 8);      // x0 x1 y0 y1
                const float4 cd = *reinterpret_cast<const float4*>(Wp + j * 8 + 4);  // z0 z1 w0 w1
                const v2f xp = {ab.x, ab.y}, yp = {ab.z, ab.w};
                const v2f zp = {cd.x, cd.y}, wp = {cd.z, cd.w};
                v2f s2 = wp + qnp2;
                s2 = __builtin_elementwise_fma(zp, m2z2, s2);
                s2 = __builtin_elementwise_fma(yp, m2y2, s2);
                s2 = __builtin_elementwise_fma(xp, m2x2, s2);
                const unsigned k0 = (__float_as_uint(s2.x) & 0xFFFFFFC0u) | (unsigned)(2 * j);
                const unsigned k1 = (__float_as_uint(s2.y) & 0xFFFFFFC0u) | (unsigned)(2 * j + 1);
                wmA = umin32(wmA, k0);
                wmB = umin32(wmB, k1);
            }
            const unsigned wm = umin32(wmA, wmB);
            const unsigned base = jb + (unsigned)(wi * WLEN);   // scalar per window
            keyout[wi] = (wm & 0xFFFFE000u) | base | (wm & 63u);
        }

#pragma unroll
        for (int wi = 0; wi < NWIN; ++wi) mrg[w][wi][lane] = keyout[wi];
        __syncthreads();

        // stage 1: waves 0..3 each merge 4 slices' window minima (self filtered)
        if (w < 4) {
            const unsigned selfidx = (unsigned)qi;
            unsigned best[KNN];
#pragma unroll
            for (int s = 0; s < KNN; ++s) best[s] = 0xFFFFFFFFu;
            for (int sl = 4 * w; sl < 4 * w + 4; ++sl) {
#pragma unroll
                for (int u = 0; u < KNN; ++u) {
                    unsigned key = mrg[sl][u][lane];
                    key = ((key & 0x1FFFu) == selfidx) ? 0xFFFFFFFFu : key;
                    INSERT8(best, key);
                }
            }
#pragma unroll
            for (int s = 0; s < KNN; ++s) mrg[4 * w][s][lane] = best[s];
        }
        __syncthreads();

        // stage 2: wave 0 merges the 4 partials; closed-form deviation sum
        if (w == 0) {
            unsigned best[KNN];
#pragma unroll
            for (int s = 0; s < KNN; ++s) best[s] = 0xFFFFFFFFu;
            for (int g = 0; g < 4; ++g) {
#pragma unroll
                for (int u = 0; u < KNN; ++u) {
                    const unsigned key = mrg[4 * g][u][lane];
                    INSERT8(best, key);
                }
            }
            float sx = 0.f, sy = 0.f, sz = 0.f, sw = 0.f;
#pragma unroll
            for (int s = 0; s < KNN; ++s) {
                const unsigned n = best[s] & 0x1FFFu;
                const float* np = B + (size_t)(n >> 1) * 8 + (n & 1);
                sx += np[0]; sy += np[2]; sz += np[4]; sw += np[6];
            }
            float ssum = sw - (sx * sx + sy * sy + sz * sz) * (1.f / KNN);
#pragma unroll
            for (int o = 32; o > 0; o >>= 1) ssum += __shfl_down(ssum, o, 64);
            if (lane == 0) atomicAdd(&acc[2], (double)ssum);
        }
    }

    // last-done block finalizes the 5 outputs
    __syncthreads();
    if (t == 0) {
        __threadfence();
        const unsigned old = atomicAdd(ctr, 1u);
        if (old == TOT_BLOCKS - 1) {
            __threadfence();
            const double a0 = atomicAdd(&acc[0], 0.0);
            const double a1 = atomicAdd(&acc[1], 0.0);
            const double a2d = atomicAdd(&acc[2], 0.0);
            const double a3 = atomicAdd(&acc[3], 0.0);
            const double a4 = atomicAdd(&acc[4], 0.0);
            const double recon  = a0 / (double)(NBATCH * NPTS * 3);
            const double percep = a1 / 4096.0;
            const double cont   = a2d / (double)(NBATCH * NPTS * KNN);
            const double bnd    = (a4 > 0.0) ? a3 / ((a4 > 1.0) ? a4 : 1.0) : 0.0;
            const double total  = recon + 0.5 * percep + 0.5 * cont + bnd;
            out[0] = (float)recon;
            out[1] = (float)percep;
            out[2] = (float)cont;
            out[3] = (float)bnd;
            out[4] = (float)total;
        }
    }
}

extern "C" void kernel_launch(void* const* d_in, const int* in_sizes, int n_in,
                              void* d_out, int out_size, void* d_ws, size_t ws_size,
                              hipStream_t stream) {
    const float* pred = (const float*)d_in[0];
    const float* targ = (const float*)d_in[1];
    const float* pf   = (const float*)d_in[2];
    const float* tf   = (const float*)d_in[3];
    const float* c1   = (const float*)d_in[4];
    const float* c2   = (const float*)d_in[5];
    float* out  = (float*)d_out;
    double* acc = (double*)d_ws;
    unsigned* ctr = (unsigned*)((char*)d_ws + CTR_OFF);
    float* pb   = (float*)((char*)d_ws + PB_OFF);
    float* c2p  = (float*)((char*)d_ws + C2_OFF);

    hipMemsetAsync(d_ws, 0, 64, stream);   // acc[0..4] + ctr
    hipLaunchKernelGGL(prep_kernel, dim3(86), dim3(512), 0, stream,
                       pred, c2, pred, targ, pf, tf, pb, c2p, acc);
    hipLaunchKernelGGL(main_kernel, dim3(TOT_BLOCKS), dim3(1024), 0, stream,
                       pb, pred, c1, c2p, acc, ctr, out);
}